// Round 9
// baseline (444.409 us; speedup 1.0000x reference)
//
#include <hip/hip_runtime.h>

// Fused 3-layer GCN (GS=7, H=144) + pool + fc, B=65536.  Round 20.
// R17/R19 both plateau at 246 us regardless of work split -> shared limiter:
// per-K-step L2 weight loads (18/wave/layer, ~200cyc, ~4 in flight at
// VGPR 64) + per-block weight re-read (190 KB x 16384 = 3.1 GB L2 ~ 90 us).
// R20 amortizes: NI=8, m-loop over 2 groups of 28 rows; each wave holds its
// Hcol-tile's full W K-column in REGISTERS per layer (wA/wB = 72 VGPR;
// waves 1/2 + tail path = 108). Loads = one batched burst per layer.
// Per-graph weight traffic halves (8192 blocks x ~200 KB = 1.6 GB).
// Mix per group via sAf: block-diag adjacency fragments prebuilt in LDS
// (conflict-free b128 reads). Accs never exceed 32; peak live ~160 at
// launch_bounds(256,3) (R11 precedent: 168 fits). LDS 52.6 KB -> 3 blk/CU.
// Per group: GEMM -> Y -> B0 -> mix -> sX -> B1 (4 barriers/layer).
//
// Algorithm (hardware-verified R14-R19): operand-role-swapped GEMM
//   (A = x rows from sX, B = W frag) -> D: lane=Hcol, regs=graph-row ->
//   written transposed as sY[Hcol][group-row] (b64, chunk-rotated) -> the
//   k-contiguous B-operand for the mix MFMA (A = block-diag adjacency).
//   x_new = 0.5*(relu(nA-mix(Y1)) + relu(iA-mix(Y2))) -> sX[row][col].
// MFMA conventions (verified R7-R19): D[n][m]: col=lane&31 (=m),
//   row=(reg&3)+8*(reg>>2)+4*(lane>>5) (=n); operand frags: arg0=A[n][k]
//   lane&31=n, k=kstep*16+(lane>>5)*8+j; arg1=B[k][m] lane&31=m, same k.
// wt layout (d_ws, unchanged): [l][p][nt0..4][ks0..8] frags of 512 halfs,
//   m=nt*32+(lane&31) (>=144 pad0), k=ks*16+(lane>>5)*8+j (>=K pad0).

typedef _Float16 half8   __attribute__((ext_vector_type(8)));
typedef _Float16 half4_t __attribute__((ext_vector_type(4)));
typedef float    floatx16 __attribute__((ext_vector_type(16)));

constexpr int GS = 7;
constexpr int NI = 8;                 // graphs per block
constexpr int NG = 2;                 // row groups per block
constexpr int GROWS = 28;             // rows per group (4 graphs x 7)
constexpr int MROWS = NI * GS;        // 56
constexpr int H = 144;
constexpr int LSTRIDE = 2 * 5 * 9 * 512;  // 46080 halfs per layer
constexpr int WT_HALFS = 3 * LSTRIDE;     // 138240
constexpr int FRAGS = 3 * 90 * 64;        // 17280 prep thread-slices
constexpr int XROW = 152;                 // sX row stride: 304B, 16B-aligned rows
constexpr int YROW = 40;                  // sY row stride: 80B, 16B-aligned rows

static __device__ inline half8 bc(_Float16 v) {
    half8 h = {v, v, v, v, v, v, v, v};
    return h;
}

// ---------------- prologue: weights -> fragment-linear fp16, g = fc2 @ fc1 ----------------
__global__ void prep_kernel(const float* __restrict__ w10, const float* __restrict__ w20,
                            const float* __restrict__ w11, const float* __restrict__ w21,
                            const float* __restrict__ w12, const float* __restrict__ w22,
                            const float* __restrict__ fc1, const float* __restrict__ fc2,
                            _Float16* __restrict__ wt, float* __restrict__ g)
{
    if (blockIdx.x == 68) {             // g = fc2 @ fc1 (both linear, no act)
        const int j = threadIdx.x;
        if (j < H) {
            float s = 0.f;
            for (int o = 0; o < 128; ++o) s = fmaf(fc2[o], fc1[o * H + j], s);
            g[j] = s;
        }
        return;
    }
    const int t = blockIdx.x * 256 + threadIdx.x;
    if (t >= FRAGS) return;
    const int l    = t / (90 * 64);
    const int r    = t - l * (90 * 64);
    const int frag = r >> 6;            // 0..89  = p*45 + nt*9 + ks
    const int lane = r & 63;
    const int p    = frag / 45;         // 0 -> W1, 1 -> W2
    const int rem  = frag - p * 45;
    const int nt   = rem / 9;           // 0..4
    const int ks   = rem - nt * 9;      // 0..8
    const int m    = nt * 32 + (lane & 31);           // out-col 0..159
    const int k0   = ks * 16 + (lane >> 5) * 8;       // in-dim base
    const float* W = (l == 0) ? (p ? w20 : w10)
                   : (l == 1) ? (p ? w21 : w11)
                              : (p ? w22 : w12);
    const int K = (l == 0) ? 5 : H;
    half8 h = bc((_Float16)0);
    #pragma unroll
    for (int j = 0; j < 8; ++j) {
        const int k = k0 + j;
        if (m < H && k < K) h[j] = (_Float16)W[k * H + m];   // lanes coalesce over m
    }
    *(half8*)(wt + (size_t)l * LSTRIDE + (size_t)frag * 512 + (size_t)lane * 8) = h;
}

// ---- one full layer: W -> regs once; per group: GEMM -> sY -> mix -> sX ----
// Straight-line, no lambdas. Barriers are workgroup-uniform.
template<int NK>
static __device__ __forceinline__ void layer_pass(const _Float16* __restrict__ wl,
        const int lane, const int wv, const int hi, const int m32, const int r0c,
        const int rot,
        _Float16 (*sX)[XROW], _Float16 (*sY1)[YROW], _Float16 (*sY2)[YROW],
        const _Float16 (*sAf)[64 * 8])
{
    // ---- load this wave's W column into registers (once per layer) ----
    half8 wA[NK], wB[NK];
    #pragma unroll
    for (int ks = 0; ks < NK; ++ks) {
        const _Float16* fb = wl + (size_t)((wv * 9 + ks) * 512) + (size_t)lane * 8;
        wA[ks] = *(const half8*)fb;               // p=0 (W1)
        wB[ks] = *(const half8*)(fb + 45 * 512);  // p=1 (W2)
    }
    half8 eT[NK];     // tail W column: wave1 holds path1, wave2 holds path2
    if (wv == 1 || wv == 2) {
        const int poff = (wv == 2) ? 45 * 512 : 0;
        #pragma unroll
        for (int ks = 0; ks < NK; ++ks)
            eT[ks] = *(const half8*)(wl + (size_t)((36 + ks) * 512) + poff + (size_t)lane * 8);
    }

    #pragma unroll
    for (int g = 0; g < NG; ++g) {
        const int rbase = g * GROWS;

        // ---------- phase A: main GEMM (own tile), Y -> LDS ----------
        {
            floatx16 a1, a2;
            #pragma unroll
            for (int i = 0; i < 16; ++i) { a1[i] = 0.f; a2[i] = 0.f; }
            #pragma unroll
            for (int ks = 0; ks < NK; ++ks) {
                const half8 xa = *(const half8*)&sX[rbase + r0c][ks * 16 + hi * 8];
                a1 = __builtin_amdgcn_mfma_f32_32x32x16_f16(xa, wA[ks], a1, 0, 0, 0);
                a2 = __builtin_amdgcn_mfma_f32_32x32x16_f16(xa, wB[ks], a2, 0, 0, 0);
            }
            const int yb = wv * 32 + m32;
            #pragma unroll
            for (int q = 0; q < 4; ++q) {
                const int n0 = (8 * q + 4 * hi + rot) & 31;
                half4_t h1, h2;
                #pragma unroll
                for (int i = 0; i < 4; ++i) {
                    h1[i] = (_Float16)a1[4 * q + i];
                    h2[i] = (_Float16)a2[4 * q + i];
                }
                *(half4_t*)&sY1[yb][n0] = h1;
                *(half4_t*)&sY2[yb][n0] = h2;
            }
        }   // a1/a2 dead

        // ---------- phase A': tail GEMM (tile 4), path-split waves 1/2 ----------
        if (wv == 1) {                                     // tail path 1 -> sY1
            floatx16 e1;
            #pragma unroll
            for (int i = 0; i < 16; ++i) e1[i] = 0.f;
            #pragma unroll
            for (int ks = 0; ks < NK; ++ks) {
                const half8 xa = *(const half8*)&sX[rbase + r0c][ks * 16 + hi * 8];
                e1 = __builtin_amdgcn_mfma_f32_32x32x16_f16(xa, eT[ks], e1, 0, 0, 0);
            }
            if (m32 < 16) {
                const int yb = 128 + m32;
                #pragma unroll
                for (int q = 0; q < 4; ++q) {
                    const int n0 = (8 * q + 4 * hi + rot) & 31;
                    half4_t h1;
                    #pragma unroll
                    for (int i = 0; i < 4; ++i) h1[i] = (_Float16)e1[4 * q + i];
                    *(half4_t*)&sY1[yb][n0] = h1;
                }
            }
        }
        if (wv == 2) {                                     // tail path 2 -> sY2
            floatx16 e2;
            #pragma unroll
            for (int i = 0; i < 16; ++i) e2[i] = 0.f;
            #pragma unroll
            for (int ks = 0; ks < NK; ++ks) {
                const half8 xa = *(const half8*)&sX[rbase + r0c][ks * 16 + hi * 8];
                e2 = __builtin_amdgcn_mfma_f32_32x32x16_f16(xa, eT[ks], e2, 0, 0, 0);
            }
            if (m32 < 16) {
                const int yb = 128 + m32;
                #pragma unroll
                for (int q = 0; q < 4; ++q) {
                    const int n0 = (8 * q + 4 * hi + rot) & 31;
                    half4_t h2;
                    #pragma unroll
                    for (int i = 0; i < 4; ++i) h2[i] = (_Float16)e2[4 * q + i];
                    *(half4_t*)&sY2[yb][n0] = h2;
                }
            }
        }

        __syncthreads();   // B0: group-g sX reads done; all Y rows written

        // ---------- phase B: mix both paths, relu-combine, x_new -> sX ----------
        {
            const half8 fN0 = *(const half8*)&sAf[(g * 2 + 0) * 2 + 0][lane * 8];
            const half8 fN1 = *(const half8*)&sAf[(g * 2 + 0) * 2 + 1][lane * 8];
            const half8 fI0 = *(const half8*)&sAf[(g * 2 + 1) * 2 + 0][lane * 8];
            const half8 fI1 = *(const half8*)&sAf[(g * 2 + 1) * 2 + 1][lane * 8];
            const int ybr = wv * 32 + m32;
            const half8 y10 = *(const half8*)&sY1[ybr][(hi * 8 + rot) & 31];
            const half8 y11 = *(const half8*)&sY1[ybr][(16 + hi * 8 + rot) & 31];
            const half8 y20 = *(const half8*)&sY2[ybr][(hi * 8 + rot) & 31];
            const half8 y21 = *(const half8*)&sY2[ybr][(16 + hi * 8 + rot) & 31];
            floatx16 m1, m2;
            #pragma unroll
            for (int i = 0; i < 16; ++i) { m1[i] = 0.f; m2[i] = 0.f; }
            m1 = __builtin_amdgcn_mfma_f32_32x32x16_f16(fN0, y10, m1, 0, 0, 0);
            m1 = __builtin_amdgcn_mfma_f32_32x32x16_f16(fN1, y11, m1, 0, 0, 0);
            m2 = __builtin_amdgcn_mfma_f32_32x32x16_f16(fI0, y20, m2, 0, 0, 0);
            m2 = __builtin_amdgcn_mfma_f32_32x32x16_f16(fI1, y21, m2, 0, 0, 0);
            const int col = wv * 32 + m32;
            #pragma unroll
            for (int q = 0; q < 4; ++q) {
                if (q < 3 || hi == 0) {          // group rows 28..31 skipped
                    #pragma unroll
                    for (int i = 0; i < 4; ++i) {
                        const int n = i + 8 * q + 4 * hi;
                        float v1 = m1[4 * q + i]; v1 = v1 > 0.f ? v1 : 0.f;
                        float v2 = m2[4 * q + i]; v2 = v2 > 0.f ? v2 : 0.f;
                        sX[rbase + n][col] = (_Float16)(0.5f * (v1 + v2));
                    }
                }
            }
        }
        if (wv == 3) {                                     // tail mix: cols 128..143
            const half8 fN0 = *(const half8*)&sAf[(g * 2 + 0) * 2 + 0][lane * 8];
            const half8 fN1 = *(const half8*)&sAf[(g * 2 + 0) * 2 + 1][lane * 8];
            const half8 fI0 = *(const half8*)&sAf[(g * 2 + 1) * 2 + 0][lane * 8];
            const half8 fI1 = *(const half8*)&sAf[(g * 2 + 1) * 2 + 1][lane * 8];
            const int ybr = 128 + (m32 < 16 ? m32 : 15);   // clamped, in-bounds
            const half8 y10 = *(const half8*)&sY1[ybr][(hi * 8 + rot) & 31];
            const half8 y11 = *(const half8*)&sY1[ybr][(16 + hi * 8 + rot) & 31];
            const half8 y20 = *(const half8*)&sY2[ybr][(hi * 8 + rot) & 31];
            const half8 y21 = *(const half8*)&sY2[ybr][(16 + hi * 8 + rot) & 31];
            floatx16 m1, m2;
            #pragma unroll
            for (int i = 0; i < 16; ++i) { m1[i] = 0.f; m2[i] = 0.f; }
            m1 = __builtin_amdgcn_mfma_f32_32x32x16_f16(fN0, y10, m1, 0, 0, 0);
            m1 = __builtin_amdgcn_mfma_f32_32x32x16_f16(fN1, y11, m1, 0, 0, 0);
            m2 = __builtin_amdgcn_mfma_f32_32x32x16_f16(fI0, y20, m2, 0, 0, 0);
            m2 = __builtin_amdgcn_mfma_f32_32x32x16_f16(fI1, y21, m2, 0, 0, 0);
            if (m32 < 16) {
                const int col = 128 + m32;
                #pragma unroll
                for (int q = 0; q < 4; ++q) {
                    if (q < 3 || hi == 0) {
                        #pragma unroll
                        for (int i = 0; i < 4; ++i) {
                            const int n = i + 8 * q + 4 * hi;
                            float v1 = m1[4 * q + i]; v1 = v1 > 0.f ? v1 : 0.f;
                            float v2 = m2[4 * q + i]; v2 = v2 > 0.f ? v2 : 0.f;
                            sX[rbase + n][col] = (_Float16)(0.5f * (v1 + v2));
                        }
                    }
                }
            }
        }

        __syncthreads();   // B1: group-g x_new visible; sY free for next group
    }
}

__global__ __launch_bounds__(256, 3)
void gcn_mfma(const float* __restrict__ ops, const float* __restrict__ adj,
              const float* __restrict__ nv,
              const _Float16* __restrict__ wt, const float* __restrict__ gw,
              float* __restrict__ out)
{
    __shared__ __align__(16) _Float16 sX [MROWS][XROW];       // 17024 B
    __shared__ __align__(16) _Float16 sY1[4 * 32 + 32][YROW]; // 12800 B
    __shared__ __align__(16) _Float16 sY2[4 * 32 + 32][YROW]; // 12800 B
    __shared__ __align__(16) _Float16 sAh[NI][2][GS][8];      //  1792 B
    __shared__ __align__(16) _Float16 sAf[8][64 * 8];         //  8192 B  total 52608 B

    float (*adjd)[GS][GS] = (float(*)[GS][GS])&sY1[0][0];     // prologue-only scratch

    const int tid  = threadIdx.x;
    const int lane = tid & 63;
    const int wv   = tid >> 6;
    const int hi   = lane >> 5;
    const int m32  = lane & 31;
    const int rot  = m32 & 24;                             // Y chunk rotation
    const int r0c  = (m32 < GROWS) ? m32 : (GROWS - 1);    // clamped group-row
    const int ibase = blockIdx.x * NI;

    // ---------------- per-block prologue: stage X (fp16), adjacency matrices ----------------
    if (tid < MROWS) {
        const int item = tid / GS, r = tid % GS;
        const float* orow = ops + ((size_t)(ibase + item) * GS + r) * 5;
        half8 h = bc((_Float16)0);
        h[0] = (_Float16)orow[0]; h[1] = (_Float16)orow[1]; h[2] = (_Float16)orow[2];
        h[3] = (_Float16)orow[3]; h[4] = (_Float16)orow[4];
        *(half8*)&sX[tid][0] = h;
        *(half8*)&sX[tid][8] = bc((_Float16)0);   // layer-0 K pad (k=5..15)

        const float* arow = adj + ((size_t)(ibase + item) * GS + r) * GS;
        float a[GS]; float sm = 0.f;
        #pragma unroll
        for (int c = 0; c < GS; ++c) { a[c] = arow[c] + (c == r ? 1.f : 0.f); sm += a[c]; }
        const float is = 1.f / sm;
        #pragma unroll
        for (int c = 0; c < GS; ++c) {
            const float v = a[c] * is;
            adjd[item][r][c] = v;
            sAh[item][0][r][c] = (_Float16)v;
        }
        sAh[item][0][r][7] = (_Float16)0.f;
    }
    __syncthreads();
    if (tid < MROWS) {    // inv_norm_adj = row_normalize(adj_d^T)
        const int item = tid / GS, r = tid % GS;
        float v[GS]; float sm = 0.f;
        #pragma unroll
        for (int k = 0; k < GS; ++k) { v[k] = adjd[item][k][r]; sm += v[k]; }
        const float is = 1.f / sm;
        #pragma unroll
        for (int k = 0; k < GS; ++k) sAh[item][1][r][k] = (_Float16)(v[k] * is);
        sAh[item][1][r][7] = (_Float16)0.f;
    }
    __syncthreads();

    // ---- build block-diagonal adjacency MFMA fragments into sAf ----
    // sAf[(g*2+p)*2+s][lane*8 + j]: A[n][k], n = lane&31, k = s*16+(lane>>5)*8+j;
    // zero outside the per-graph 7x7 diagonal blocks and for n,k >= 28.
    #pragma unroll
    for (int rep = 0; rep < 2; ++rep) {
        const int e  = tid + rep * 256;
        const int gg = e >> 8, pp = (e >> 7) & 1, ss = (e >> 6) & 1, ll = e & 63;
        const int hh = ll >> 5, nn = ll & 31;
        const int gA = nn / 7, rA = nn - 7 * gA;
        half8 f = bc((_Float16)0);
        #pragma unroll
        for (int j = 0; j < 8; ++j) {
            const int k  = ss * 16 + hh * 8 + j;
            const int gK = k / 7, rK = k - 7 * gK;
            if (nn < GROWS && k < GROWS && gK == gA)
                f[j] = sAh[gg * 4 + gA][pp][rA][rK];
        }
        *(half8*)&sAf[(gg * 2 + pp) * 2 + ss][ll * 8] = f;
    }
    __syncthreads();   // sAf ready (also covers adjd scratch death before sY1 use)

    // ==================== 3 layers ====================
    layer_pass<1>(wt,                       lane, wv, hi, m32, r0c, rot, sX, sY1, sY2, sAf);
    layer_pass<9>(wt + (size_t)1 * LSTRIDE, lane, wv, hi, m32, r0c, rot, sX, sY1, sY2, sAf);
    layer_pass<9>(wt + (size_t)2 * LSTRIDE, lane, wv, hi, m32, r0c, rot, sX, sY1, sY2, sAf);

    // ==================== pool + (fc2@fc1) dot ====================
    if (tid < NI * 16) {
        const int item = tid >> 4, part = tid & 15;
        float s = 0.f;
        #pragma unroll
        for (int c = 0; c < 9; ++c) {
            const int j = part * 9 + c;
            const float gj = gw[j];
            #pragma unroll
            for (int i = 0; i < GS; ++i)
                s = fmaf((float)sX[item * GS + i][j], gj, s);
        }
        s += __shfl_xor(s, 1);
        s += __shfl_xor(s, 2);
        s += __shfl_xor(s, 4);
        s += __shfl_xor(s, 8);
        if (part == 0) out[ibase + item] = s / nv[ibase + item];
    }
}

extern "C" void kernel_launch(void* const* d_in, const int* in_sizes, int n_in,
                              void* d_out, int out_size, void* d_ws, size_t ws_size,
                              hipStream_t stream) {
    const float* ops = (const float*)d_in[0];
    const float* adj = (const float*)d_in[1];
    const float* nv  = (const float*)d_in[2];
    const float* w10 = (const float*)d_in[3];
    const float* w20 = (const float*)d_in[4];
    const float* w11 = (const float*)d_in[5];
    const float* w21 = (const float*)d_in[6];
    const float* w12 = (const float*)d_in[7];
    const float* w22 = (const float*)d_in[8];
    const float* fc1 = (const float*)d_in[9];
    const float* fc2 = (const float*)d_in[10];

    _Float16* wt = (_Float16*)d_ws;                              // 276480 B
    float*    g  = (float*)((char*)d_ws + (size_t)WT_HALFS * 2); // 576 B

    prep_kernel<<<69, 256, 0, stream>>>(w10, w20, w11, w21, w12, w22,
                                        fc1, fc2, wt, g);
    gcn_mfma<<<65536 / NI, 256, 0, stream>>>(ops, adj, nv, wt, g, (float*)d_out);
}

// Round 10
// 286.626 us; speedup vs baseline: 1.5505x; 1.5505x over previous
//
#include <hip/hip_runtime.h>

// Fused 3-layer GCN (GS=7, H=144) + pool + fc, B=65536.  Round 21.
// R20 spilled (497 MB WRITE, my liveness audit missed W-regs live across
// the group loop into phase B: ~190 > 170 cap). Session rule, now strict:
// concurrent live set must stay <= ~110. R21 = R19 body (spill-free,
// 246 us) + the R20 latency fix applied WITHIN that budget:
//   phase A split into two half-passes: p1 batch-loads 9 W1 frags (36 regs)
//     -> a1 (16 accs) -> Y1; p2 same for W2 -> Y2. Peak ~97. The batch
//     issues 9 independent L2 loads back-to-back (R19: VGPR 64 allowed
//     only ~2-3 in flight -> ~5 serialized ~220cyc stalls per wave-layer).
//   tail waves 1/2 batch their 9 tail frags the same way after main.
//   adjacency mix frags in LDS (sAf, 4 KB; R20 piece that worked):
//     -16 always-live regs; phase B peak ~109.
// launch_bounds(256,4); LDS 36544 B x 4 blocks = 146 KB <= 160 ✓.
//
// Algorithm (hardware-verified R14-R20): operand-role-swapped GEMM
//   (A = x rows from sX, B = W frag) -> D: lane=Hcol, regs=graph-row ->
//   written transposed as sY[Hcol][row] (b64, chunk-rotated) -> the
//   k-contiguous B-operand for the mix MFMA (A = block-diag adjacency from
//   sAf). x_new = 0.5*(relu(nA-mix(Y1)) + relu(iA-mix(Y2))) -> sX[row][col].
// Tiling: 5 Hcol tiles of 32 (tile 4 = cols 128..143); wave wv owns tile wv;
// tail GEMM p1 -> wave1, p2 -> wave2; tail mix -> wave3. 2 barriers/layer.
// MFMA conventions (verified R7-R20): D[n][m]: col=lane&31 (=m),
//   row=(reg&3)+8*(reg>>2)+4*(lane>>5) (=n); operand frags: arg0=A[n][k]
//   lane&31=n, k=kstep*16+(lane>>5)*8+j; arg1=B[k][m] lane&31=m, same k.
// wt layout (d_ws): [l][p][nt0..4][ks0..8] frags of 512 halfs,
//   m=nt*32+(lane&31) (>=144 pad0), k=ks*16+(lane>>5)*8+j (>=K pad0).

typedef _Float16 half8   __attribute__((ext_vector_type(8)));
typedef _Float16 half4_t __attribute__((ext_vector_type(4)));
typedef float    floatx16 __attribute__((ext_vector_type(16)));

constexpr int GS = 7;
constexpr int NI = 4;                 // graphs per block
constexpr int MROWS = NI * GS;        // 28
constexpr int H = 144;
constexpr int LSTRIDE = 2 * 5 * 9 * 512;  // 46080 halfs per layer
constexpr int WT_HALFS = 3 * LSTRIDE;     // 138240
constexpr int FRAGS = 3 * 90 * 64;        // 17280 prep thread-slices
constexpr int XROW = 152;                 // sX row stride: 304B, 16B-aligned rows
constexpr int YROW = 40;                  // sY row stride: 80B, 16B-aligned rows

static __device__ inline half8 bc(_Float16 v) {
    half8 h = {v, v, v, v, v, v, v, v};
    return h;
}

// ---------------- prologue: weights -> fragment-linear fp16, g = fc2 @ fc1 ----------------
__global__ void prep_kernel(const float* __restrict__ w10, const float* __restrict__ w20,
                            const float* __restrict__ w11, const float* __restrict__ w21,
                            const float* __restrict__ w12, const float* __restrict__ w22,
                            const float* __restrict__ fc1, const float* __restrict__ fc2,
                            _Float16* __restrict__ wt, float* __restrict__ g)
{
    if (blockIdx.x == 68) {             // g = fc2 @ fc1 (both linear, no act)
        const int j = threadIdx.x;
        if (j < H) {
            float s = 0.f;
            for (int o = 0; o < 128; ++o) s = fmaf(fc2[o], fc1[o * H + j], s);
            g[j] = s;
        }
        return;
    }
    const int t = blockIdx.x * 256 + threadIdx.x;
    if (t >= FRAGS) return;
    const int l    = t / (90 * 64);
    const int r    = t - l * (90 * 64);
    const int frag = r >> 6;            // 0..89  = p*45 + nt*9 + ks
    const int lane = r & 63;
    const int p    = frag / 45;         // 0 -> W1, 1 -> W2
    const int rem  = frag - p * 45;
    const int nt   = rem / 9;           // 0..4
    const int ks   = rem - nt * 9;      // 0..8
    const int m    = nt * 32 + (lane & 31);           // out-col 0..159
    const int k0   = ks * 16 + (lane >> 5) * 8;       // in-dim base
    const float* W = (l == 0) ? (p ? w20 : w10)
                   : (l == 1) ? (p ? w21 : w11)
                              : (p ? w22 : w12);
    const int K = (l == 0) ? 5 : H;
    half8 h = bc((_Float16)0);
    #pragma unroll
    for (int j = 0; j < 8; ++j) {
        const int k = k0 + j;
        if (m < H && k < K) h[j] = (_Float16)W[k * H + m];   // lanes coalesce over m
    }
    *(half8*)(wt + (size_t)l * LSTRIDE + (size_t)frag * 512 + (size_t)lane * 8) = h;
}

// ---- one full layer: half-pass GEMMs (batched W) -> sY1/sY2 -> mix -> sX ----
// Straight-line, no lambdas; every scope keeps concurrent live regs <= ~110.
// Barriers are workgroup-uniform.
template<int NK>
static __device__ __forceinline__ void layer_pass(const _Float16* __restrict__ wl,
        const int lane, const int wv, const int hi, const int m32, const int r0c,
        const int rot,
        _Float16 (*sX)[XROW], _Float16 (*sY1)[YROW], _Float16 (*sY2)[YROW],
        const _Float16 (*sAf)[64 * 8])
{
    // ---------- phase A p1: W1 batch -> a1 -> sY1 ----------
    {
        half8 wA[NK];
        #pragma unroll
        for (int ks = 0; ks < NK; ++ks)     // 9 independent L2 loads, batch issue
            wA[ks] = *(const half8*)(wl + (size_t)((wv * 9 + ks) * 512) + (size_t)lane * 8);
        floatx16 a1;
        #pragma unroll
        for (int i = 0; i < 16; ++i) a1[i] = 0.f;
        #pragma unroll
        for (int ks = 0; ks < NK; ++ks) {
            const half8 xa = *(const half8*)&sX[r0c][ks * 16 + hi * 8];
            a1 = __builtin_amdgcn_mfma_f32_32x32x16_f16(xa, wA[ks], a1, 0, 0, 0);
        }
        const int yb = wv * 32 + m32;
        #pragma unroll
        for (int q = 0; q < 4; ++q) {
            const int n0 = (8 * q + 4 * hi + rot) & 31;
            half4_t h1;
            #pragma unroll
            for (int i = 0; i < 4; ++i) h1[i] = (_Float16)a1[4 * q + i];
            *(half4_t*)&sY1[yb][n0] = h1;
        }
    }   // wA/a1 dead

    // ---------- phase A p2: W2 batch -> a2 -> sY2 ----------
    {
        half8 wB[NK];
        #pragma unroll
        for (int ks = 0; ks < NK; ++ks)
            wB[ks] = *(const half8*)(wl + (size_t)((wv * 9 + ks) * 512) + 45 * 512
                                        + (size_t)lane * 8);
        floatx16 a2;
        #pragma unroll
        for (int i = 0; i < 16; ++i) a2[i] = 0.f;
        #pragma unroll
        for (int ks = 0; ks < NK; ++ks) {
            const half8 xa = *(const half8*)&sX[r0c][ks * 16 + hi * 8];
            a2 = __builtin_amdgcn_mfma_f32_32x32x16_f16(xa, wB[ks], a2, 0, 0, 0);
        }
        const int yb = wv * 32 + m32;
        #pragma unroll
        for (int q = 0; q < 4; ++q) {
            const int n0 = (8 * q + 4 * hi + rot) & 31;
            half4_t h2;
            #pragma unroll
            for (int i = 0; i < 4; ++i) h2[i] = (_Float16)a2[4 * q + i];
            *(half4_t*)&sY2[yb][n0] = h2;
        }
    }   // wB/a2 dead

    // ---------- phase A': tail GEMM (tile 4), path-split waves 1/2, batched ----------
    if (wv == 1) {                                         // tail path 1 -> sY1
        half8 eW[NK];
        #pragma unroll
        for (int ks = 0; ks < NK; ++ks)
            eW[ks] = *(const half8*)(wl + (size_t)((36 + ks) * 512) + (size_t)lane * 8);
        floatx16 e1;
        #pragma unroll
        for (int i = 0; i < 16; ++i) e1[i] = 0.f;
        #pragma unroll
        for (int ks = 0; ks < NK; ++ks) {
            const half8 xa = *(const half8*)&sX[r0c][ks * 16 + hi * 8];
            e1 = __builtin_amdgcn_mfma_f32_32x32x16_f16(xa, eW[ks], e1, 0, 0, 0);
        }
        if (m32 < 16) {
            const int yb = 128 + m32;
            #pragma unroll
            for (int q = 0; q < 4; ++q) {
                const int n0 = (8 * q + 4 * hi + rot) & 31;
                half4_t h1;
                #pragma unroll
                for (int i = 0; i < 4; ++i) h1[i] = (_Float16)e1[4 * q + i];
                *(half4_t*)&sY1[yb][n0] = h1;
            }
        }
    }
    if (wv == 2) {                                         // tail path 2 -> sY2
        half8 eW[NK];
        #pragma unroll
        for (int ks = 0; ks < NK; ++ks)
            eW[ks] = *(const half8*)(wl + (size_t)((81 + ks) * 512) + (size_t)lane * 8);
        floatx16 e2;
        #pragma unroll
        for (int i = 0; i < 16; ++i) e2[i] = 0.f;
        #pragma unroll
        for (int ks = 0; ks < NK; ++ks) {
            const half8 xa = *(const half8*)&sX[r0c][ks * 16 + hi * 8];
            e2 = __builtin_amdgcn_mfma_f32_32x32x16_f16(xa, eW[ks], e2, 0, 0, 0);
        }
        if (m32 < 16) {
            const int yb = 128 + m32;
            #pragma unroll
            for (int q = 0; q < 4; ++q) {
                const int n0 = (8 * q + 4 * hi + rot) & 31;
                half4_t h2;
                #pragma unroll
                for (int i = 0; i < 4; ++i) h2[i] = (_Float16)e2[4 * q + i];
                *(half4_t*)&sY2[yb][n0] = h2;
            }
        }
    }

    __syncthreads();   // B0: all sX reads done; all Y rows written

    // ---------- phase B: mix both paths (frags from sAf), combine, -> sX ----------
    {
        const half8 fN0 = *(const half8*)&sAf[0][lane * 8];
        const half8 fN1 = *(const half8*)&sAf[1][lane * 8];
        const half8 fI0 = *(const half8*)&sAf[2][lane * 8];
        const half8 fI1 = *(const half8*)&sAf[3][lane * 8];
        const int ybr = wv * 32 + m32;                     // tiles 0..3: rows valid
        const half8 y10 = *(const half8*)&sY1[ybr][(hi * 8 + rot) & 31];
        const half8 y11 = *(const half8*)&sY1[ybr][(16 + hi * 8 + rot) & 31];
        const half8 y20 = *(const half8*)&sY2[ybr][(hi * 8 + rot) & 31];
        const half8 y21 = *(const half8*)&sY2[ybr][(16 + hi * 8 + rot) & 31];
        floatx16 m1, m2;
        #pragma unroll
        for (int i = 0; i < 16; ++i) { m1[i] = 0.f; m2[i] = 0.f; }
        m1 = __builtin_amdgcn_mfma_f32_32x32x16_f16(fN0, y10, m1, 0, 0, 0);
        m1 = __builtin_amdgcn_mfma_f32_32x32x16_f16(fN1, y11, m1, 0, 0, 0);
        m2 = __builtin_amdgcn_mfma_f32_32x32x16_f16(fI0, y20, m2, 0, 0, 0);
        m2 = __builtin_amdgcn_mfma_f32_32x32x16_f16(fI1, y21, m2, 0, 0, 0);
        const int col = wv * 32 + m32;
        #pragma unroll
        for (int q = 0; q < 4; ++q) {
            if (q < 3 || hi == 0) {          // rows 28..31 skipped
                #pragma unroll
                for (int i = 0; i < 4; ++i) {
                    const int n = i + 8 * q + 4 * hi;
                    float v1 = m1[4 * q + i]; v1 = v1 > 0.f ? v1 : 0.f;
                    float v2 = m2[4 * q + i]; v2 = v2 > 0.f ? v2 : 0.f;
                    sX[n][col] = (_Float16)(0.5f * (v1 + v2));
                }
            }
        }
    }
    if (wv == 3) {                                         // tail mix: cols 128..143
        const half8 fN0 = *(const half8*)&sAf[0][lane * 8];
        const half8 fN1 = *(const half8*)&sAf[1][lane * 8];
        const half8 fI0 = *(const half8*)&sAf[2][lane * 8];
        const half8 fI1 = *(const half8*)&sAf[3][lane * 8];
        const int ybr = 128 + (m32 < 16 ? m32 : 15);       // clamped, in-bounds
        const half8 y10 = *(const half8*)&sY1[ybr][(hi * 8 + rot) & 31];
        const half8 y11 = *(const half8*)&sY1[ybr][(16 + hi * 8 + rot) & 31];
        const half8 y20 = *(const half8*)&sY2[ybr][(hi * 8 + rot) & 31];
        const half8 y21 = *(const half8*)&sY2[ybr][(16 + hi * 8 + rot) & 31];
        floatx16 m1, m2;
        #pragma unroll
        for (int i = 0; i < 16; ++i) { m1[i] = 0.f; m2[i] = 0.f; }
        m1 = __builtin_amdgcn_mfma_f32_32x32x16_f16(fN0, y10, m1, 0, 0, 0);
        m1 = __builtin_amdgcn_mfma_f32_32x32x16_f16(fN1, y11, m1, 0, 0, 0);
        m2 = __builtin_amdgcn_mfma_f32_32x32x16_f16(fI0, y20, m2, 0, 0, 0);
        m2 = __builtin_amdgcn_mfma_f32_32x32x16_f16(fI1, y21, m2, 0, 0, 0);
        if (m32 < 16) {
            const int col = 128 + m32;
            #pragma unroll
            for (int q = 0; q < 4; ++q) {
                if (q < 3 || hi == 0) {      // rows 28..31 skipped
                    #pragma unroll
                    for (int i = 0; i < 4; ++i) {
                        const int n = i + 8 * q + 4 * hi;
                        float v1 = m1[4 * q + i]; v1 = v1 > 0.f ? v1 : 0.f;
                        float v2 = m2[4 * q + i]; v2 = v2 > 0.f ? v2 : 0.f;
                        sX[n][col] = (_Float16)(0.5f * (v1 + v2));
                    }
                }
            }
        }
    }

    __syncthreads();   // B1: x_new visible for next layer / pool
}

__global__ __launch_bounds__(256, 4)
void gcn_mfma(const float* __restrict__ ops, const float* __restrict__ adj,
              const float* __restrict__ nv,
              const _Float16* __restrict__ wt, const float* __restrict__ gw,
              float* __restrict__ out)
{
    __shared__ __align__(16) _Float16 sX [MROWS][XROW];       //  8512 B
    __shared__ __align__(16) _Float16 sY1[4 * 32 + 16][YROW]; // 11520 B
    __shared__ __align__(16) _Float16 sY2[4 * 32 + 16][YROW]; // 11520 B
    __shared__ __align__(16) _Float16 sAh[NI][2][GS][8];      //   896 B
    __shared__ __align__(16) _Float16 sAf[4][64 * 8];         //  4096 B  total 36544 B

    float (*adjd)[GS][GS] = (float(*)[GS][GS])&sY1[0][0];     // prologue-only scratch

    const int tid  = threadIdx.x;
    const int lane = tid & 63;
    const int wv   = tid >> 6;
    const int hi   = lane >> 5;
    const int m32  = lane & 31;
    const int rot  = m32 & 24;                           // Y chunk rotation
    const int r0c  = (m32 < MROWS) ? m32 : (MROWS - 1);  // clamped A-row for GEMM
    const int ibase = blockIdx.x * NI;

    // ---------------- per-block prologue: stage X (fp16), adjacency matrices ----------------
    if (tid < MROWS) {
        const int item = tid / GS, r = tid % GS;
        const float* orow = ops + ((size_t)(ibase + item) * GS + r) * 5;
        half8 h = bc((_Float16)0);
        h[0] = (_Float16)orow[0]; h[1] = (_Float16)orow[1]; h[2] = (_Float16)orow[2];
        h[3] = (_Float16)orow[3]; h[4] = (_Float16)orow[4];
        *(half8*)&sX[tid][0] = h;
        *(half8*)&sX[tid][8] = bc((_Float16)0);   // layer-0 K pad (k=5..15)

        const float* arow = adj + ((size_t)(ibase + item) * GS + r) * GS;
        float a[GS]; float sm = 0.f;
        #pragma unroll
        for (int c = 0; c < GS; ++c) { a[c] = arow[c] + (c == r ? 1.f : 0.f); sm += a[c]; }
        const float is = 1.f / sm;
        #pragma unroll
        for (int c = 0; c < GS; ++c) {
            const float v = a[c] * is;
            adjd[item][r][c] = v;
            sAh[item][0][r][c] = (_Float16)v;
        }
        sAh[item][0][r][7] = (_Float16)0.f;
    }
    __syncthreads();
    if (tid < MROWS) {    // inv_norm_adj = row_normalize(adj_d^T)
        const int item = tid / GS, r = tid % GS;
        float v[GS]; float sm = 0.f;
        #pragma unroll
        for (int k = 0; k < GS; ++k) { v[k] = adjd[item][k][r]; sm += v[k]; }
        const float is = 1.f / sm;
        #pragma unroll
        for (int k = 0; k < GS; ++k) sAh[item][1][r][k] = (_Float16)(v[k] * is);
        sAh[item][1][r][7] = (_Float16)0.f;
    }
    __syncthreads();

    // ---- build block-diagonal adjacency MFMA fragments into sAf ----
    // sAf[p*2+s][ll*8 + j]: A[n][k], n = ll&31, k = s*16+(ll>>5)*8+j; zero
    // outside the per-graph 7x7 diagonal blocks and for n,k >= 28.
    {
        const int pp = tid >> 7, ss = (tid >> 6) & 1, ll = tid & 63;
        const int hh = ll >> 5, nn = ll & 31;
        const int gA = nn / 7, rA = nn - 7 * gA;
        half8 f = bc((_Float16)0);
        #pragma unroll
        for (int j = 0; j < 8; ++j) {
            const int k  = ss * 16 + hh * 8 + j;
            const int gK = k / 7, rK = k - 7 * gK;
            if (nn < MROWS && k < MROWS && gK == gA)
                f[j] = sAh[gA][pp][rA][rK];
        }
        *(half8*)&sAf[pp * 2 + ss][ll * 8] = f;
    }
    __syncthreads();   // sAf ready; adjd scratch dead before sY1 reuse

    // ==================== 3 layers ====================
    layer_pass<1>(wt,                       lane, wv, hi, m32, r0c, rot, sX, sY1, sY2, sAf);
    layer_pass<9>(wt + (size_t)1 * LSTRIDE, lane, wv, hi, m32, r0c, rot, sX, sY1, sY2, sAf);
    layer_pass<9>(wt + (size_t)2 * LSTRIDE, lane, wv, hi, m32, r0c, rot, sX, sY1, sY2, sAf);

    // ==================== pool + (fc2@fc1) dot ====================
    if (tid < NI * 16) {
        const int item = tid >> 4, part = tid & 15;
        float s = 0.f;
        #pragma unroll
        for (int c = 0; c < 9; ++c) {
            const int j = part * 9 + c;
            const float gj = gw[j];
            #pragma unroll
            for (int i = 0; i < GS; ++i)
                s = fmaf((float)sX[item * GS + i][j], gj, s);
        }
        s += __shfl_xor(s, 1);
        s += __shfl_xor(s, 2);
        s += __shfl_xor(s, 4);
        s += __shfl_xor(s, 8);
        if (part == 0) out[ibase + item] = s / nv[ibase + item];
    }
}

extern "C" void kernel_launch(void* const* d_in, const int* in_sizes, int n_in,
                              void* d_out, int out_size, void* d_ws, size_t ws_size,
                              hipStream_t stream) {
    const float* ops = (const float*)d_in[0];
    const float* adj = (const float*)d_in[1];
    const float* nv  = (const float*)d_in[2];
    const float* w10 = (const float*)d_in[3];
    const float* w20 = (const float*)d_in[4];
    const float* w11 = (const float*)d_in[5];
    const float* w21 = (const float*)d_in[6];
    const float* w12 = (const float*)d_in[7];
    const float* w22 = (const float*)d_in[8];
    const float* fc1 = (const float*)d_in[9];
    const float* fc2 = (const float*)d_in[10];

    _Float16* wt = (_Float16*)d_ws;                              // 276480 B
    float*    g  = (float*)((char*)d_ws + (size_t)WT_HALFS * 2); // 576 B

    prep_kernel<<<69, 256, 0, stream>>>(w10, w20, w11, w21, w12, w22,
                                        fc1, fc2, wt, g);
    gcn_mfma<<<65536 / NI, 256, 0, stream>>>(ops, adj, nv, wt, g, (float*)d_out);
}